// Round 7
// baseline (211.970 us; speedup 1.0000x reference)
//
#include <hip/hip_runtime.h>

#define NDIM 2
#define NCELLS 200
#define BATCH 128
#define NPTS (BATCH * NCELLS)      /* 25600 */
#define NBLK (NPTS / 32)           /* 800: 32 points per wave, 2 chains */
#define XROW (2 + NCELLS * NDIM + 5) /* 407 */
#define DT_F 0.001f

typedef _Float16 v4h __attribute__((ext_vector_type(4)));
typedef float    v4f __attribute__((ext_vector_type(4)));

#define MFMA16(A, B, C) __builtin_amdgcn_mfma_f32_16x16x16f16((A), (B), (C), 0, 0, 0)

__device__ __forceinline__ float softplus_f(float z) {
    float e = __expf(-fabsf(z));
    return fmaxf(z, 0.0f) + __logf(1.0f + e);
}

// MFMA 16x16x16 f16 layouts (m89-verified family):
//   A[m][k]: m = lane&15, k = (lane>>4)*4 + i
//   B[k][n]: n = lane&15, k = (lane>>4)*4 + i
//   C/D[m][n]: n = lane&15, m = (lane>>4)*4 + reg
// D of one layer == B-layout of the next -> no cross-lane movement, no LDS.
// Two independent 16-point chains per wave for in-wave ILP (round-6 lesson:
// 1.56 waves/SIMD can't hide the serial MFMA->exp->log chain latency).

__global__ void __launch_bounds__(64, 1) phinn_kernel(
    const float* __restrict__ w0, const float* __restrict__ b0,
    const float* __restrict__ w1, const float* __restrict__ b1,
    const float* __restrict__ w2, const float* __restrict__ b2,
    const float* __restrict__ w3, const float* __restrict__ b3,
    const float* __restrict__ w4, const float* __restrict__ b4,
    const float* __restrict__ wt, const float* __restrict__ x,
    float* __restrict__ out)
{
    const int lane = threadIdx.x;     // 1 wave per block
    const int g = lane >> 4;          // k-group 0..3
    const int m = lane & 15;          // row (A) / col (B,C/D) index

    // ---------- one-time weight fragment preload (registers, f16) ----------
    v4h fW0, fW0T, fW1[2], fW1T[2], fW2[2][2], fW2T[2][2], fW3[2], fW3T[2];
    #pragma unroll
    for (int i = 0; i < 4; ++i) {
        const int k = 4 * g + i;
        fW0[i] = (k < 2) ? (_Float16)w0[m * 2 + k] : (_Float16)0.f;
        #pragma unroll
        for (int t = 0; t < 2; ++t) {
            fW1[t][i]  = (_Float16)w1[(16 * t + m) * 16 + k];
            fW3[t][i]  = (_Float16)w3[m * 32 + 16 * t + k];
            fW1T[t][i] = (_Float16)w1[(16 * t + k) * 16 + m];
            fW3T[t][i] = (_Float16)w3[k * 32 + 16 * t + m];
            #pragma unroll
            for (int u = 0; u < 2; ++u) {
                fW2[t][u][i]  = (_Float16)w2[(16 * t + m) * 32 + 16 * u + k];
                fW2T[t][u][i] = (_Float16)w2[(16 * u + k) * 32 + 16 * t + m];
            }
        }
        fW0T[i] = (m < 2) ? (_Float16)w0[k * 2 + m] : (_Float16)0.f;
    }
    float b0v[4], b1v[8], b2v[8], b3v[4], w4v[4];
    #pragma unroll
    for (int r = 0; r < 4; ++r) {
        b0v[r] = b0[4 * g + r];
        b1v[r] = b1[4 * g + r];      b1v[4 + r] = b1[16 + 4 * g + r];
        b2v[r] = b2[4 * g + r];      b2v[4 + r] = b2[16 + 4 * g + r];
        b3v[r] = b3[4 * g + r];
        w4v[r] = w4[4 * g + r];
    }
    const float wt00 = wt[0], wt01 = wt[1], wt10 = wt[2], wt11 = wt[3];

    // ---------- per-chain state (2 chains: points p, p+16) ----------
    float y0c[2], y1c[2], tsc[2], sp0c[2];
    float tl0c[2], tl1c[2], th0c[2], th1c[2];
    int pc[2];
    #pragma unroll
    for (int c = 0; c < 2; ++c) {
        const int p = blockIdx.x * 32 + 16 * c + m;
        pc[c] = p;
        const int bi = p / NCELLS;
        const int ci = p - bi * NCELLS;
        const float* xr = x + bi * XROW;
        y0c[c] = xr[2 + 2 * ci];
        y1c[c] = xr[3 + 2 * ci];
        tsc[c] = xr[0];
        sp0c[c] = xr[XROW - 5];
        const float sg_lo0 = xr[XROW - 4], sg_lo1 = xr[XROW - 3];
        const float sg_hi0 = xr[XROW - 2], sg_hi1 = xr[XROW - 1];
        tl0c[c] = sg_lo0 * wt00 + sg_lo1 * wt01;
        tl1c[c] = sg_lo0 * wt10 + sg_lo1 * wt11;
        th0c[c] = sg_hi0 * wt00 + sg_hi1 * wt01;
        th1c[c] = sg_hi0 * wt10 + sg_hi1 * wt11;
    }

    const int nsteps = (int)((x[1] - x[0]) / DT_F + 0.5f);
    const v4f zf = {0.f, 0.f, 0.f, 0.f};

    v4h fY[2];
    #pragma unroll
    for (int c = 0; c < 2; ++c) {
        fY[c][0] = (g == 0) ? (_Float16)y0c[c] : (_Float16)0.f;
        fY[c][1] = (g == 0) ? (_Float16)y1c[c] : (_Float16)0.f;
        fY[c][2] = (_Float16)0.f; fY[c][3] = (_Float16)0.f;
    }

    #pragma unroll 1
    for (int it = 0; it < nsteps; ++it) {
        // ---- L1 ----
        v4f z1[2];
        #pragma unroll
        for (int c = 0; c < 2; ++c) {
            v4f acc = {b0v[0], b0v[1], b0v[2], b0v[3]};
            z1[c] = MFMA16(fW0, fY[c], acc);
        }
        v4h a1h[2]; float sp1[2][4];
        #pragma unroll
        for (int c = 0; c < 2; ++c)
            #pragma unroll
            for (int i = 0; i < 4; ++i) {
                float a = softplus_f(z1[c][i]);
                sp1[c][i] = 1.0f - __expf(-a);
                a1h[c][i] = (_Float16)a;
            }
        // ---- L2 ----
        v4f z20[2], z21[2];
        #pragma unroll
        for (int c = 0; c < 2; ++c) {
            v4f acc0 = {b1v[0], b1v[1], b1v[2], b1v[3]};
            v4f acc1 = {b1v[4], b1v[5], b1v[6], b1v[7]};
            z20[c] = MFMA16(fW1[0], a1h[c], acc0);
            z21[c] = MFMA16(fW1[1], a1h[c], acc1);
        }
        v4h a2h0[2], a2h1[2]; float sp2[2][8];
        #pragma unroll
        for (int c = 0; c < 2; ++c)
            #pragma unroll
            for (int i = 0; i < 4; ++i) {
                float a = softplus_f(z20[c][i]);
                sp2[c][i] = 1.0f - __expf(-a);
                a2h0[c][i] = (_Float16)a;
                float b = softplus_f(z21[c][i]);
                sp2[c][4 + i] = 1.0f - __expf(-b);
                a2h1[c][i] = (_Float16)b;
            }
        // ---- L3 ----
        v4f z30[2], z31[2];
        #pragma unroll
        for (int c = 0; c < 2; ++c) {
            v4f acc0 = {b2v[0], b2v[1], b2v[2], b2v[3]};
            v4f acc1 = {b2v[4], b2v[5], b2v[6], b2v[7]};
            acc0 = MFMA16(fW2[0][0], a2h0[c], acc0);
            z30[c] = MFMA16(fW2[0][1], a2h1[c], acc0);
            acc1 = MFMA16(fW2[1][0], a2h0[c], acc1);
            z31[c] = MFMA16(fW2[1][1], a2h1[c], acc1);
        }
        v4h a3h0[2], a3h1[2]; float sp3[2][8];
        #pragma unroll
        for (int c = 0; c < 2; ++c)
            #pragma unroll
            for (int i = 0; i < 4; ++i) {
                float a = softplus_f(z30[c][i]);
                sp3[c][i] = 1.0f - __expf(-a);
                a3h0[c][i] = (_Float16)a;
                float b = softplus_f(z31[c][i]);
                sp3[c][4 + i] = 1.0f - __expf(-b);
                a3h1[c][i] = (_Float16)b;
            }
        // ---- L4 + g4 ----
        v4h g4h[2];
        #pragma unroll
        for (int c = 0; c < 2; ++c) {
            v4f acc = {b3v[0], b3v[1], b3v[2], b3v[3]};
            acc = MFMA16(fW3[0], a3h0[c], acc);
            acc = MFMA16(fW3[1], a3h1[c], acc);
            #pragma unroll
            for (int i = 0; i < 4; ++i) {
                float a = softplus_f(acc[i]);
                g4h[c][i] = (_Float16)(w4v[i] * (1.0f - __expf(-a)));
            }
        }
        // ---- g3 ----
        v4h g3h0[2], g3h1[2];
        #pragma unroll
        for (int c = 0; c < 2; ++c) {
            v4f s0 = MFMA16(fW3T[0], g4h[c], zf);
            v4f s1 = MFMA16(fW3T[1], g4h[c], zf);
            #pragma unroll
            for (int i = 0; i < 4; ++i) {
                g3h0[c][i] = (_Float16)(s0[i] * sp3[c][i]);
                g3h1[c][i] = (_Float16)(s1[i] * sp3[c][4 + i]);
            }
        }
        // ---- g2 ----
        v4h g2h0[2], g2h1[2];
        #pragma unroll
        for (int c = 0; c < 2; ++c) {
            v4f u0 = MFMA16(fW2T[0][0], g3h0[c], zf);
            u0 = MFMA16(fW2T[0][1], g3h1[c], u0);
            v4f u1 = MFMA16(fW2T[1][0], g3h0[c], zf);
            u1 = MFMA16(fW2T[1][1], g3h1[c], u1);
            #pragma unroll
            for (int i = 0; i < 4; ++i) {
                g2h0[c][i] = (_Float16)(u0[i] * sp2[c][i]);
                g2h1[c][i] = (_Float16)(u1[i] * sp2[c][4 + i]);
            }
        }
        // ---- g1 + gy + update ----
        #pragma unroll
        for (int c = 0; c < 2; ++c) {
            v4f w = MFMA16(fW1T[0], g2h0[c], zf);
            w = MFMA16(fW1T[1], g2h1[c], w);
            v4h g1h;
            #pragma unroll
            for (int i = 0; i < 4; ++i)
                g1h[i] = (_Float16)(w[i] * sp1[c][i]);
            v4f gy = MFMA16(fW0T, g1h, zf);

            const bool lo = tsc[c] < sp0c[c];
            const float tilt0 = lo ? tl0c[c] : th0c[c];
            const float tilt1 = lo ? tl1c[c] : th1c[c];
            y0c[c] = fmaf(-(gy[0] + tilt0), DT_F, y0c[c]);
            y1c[c] = fmaf(-(gy[1] + tilt1), DT_F, y1c[c]);
            tsc[c] += DT_F;
            fY[c][0] = (g == 0) ? (_Float16)y0c[c] : (_Float16)0.f;
            fY[c][1] = (g == 0) ? (_Float16)y1c[c] : (_Float16)0.f;
        }
    }

    if (g == 0) {
        #pragma unroll
        for (int c = 0; c < 2; ++c) {
            out[2 * pc[c] + 0] = y0c[c];
            out[2 * pc[c] + 1] = y1c[c];
        }
    }
}

extern "C" void kernel_launch(void* const* d_in, const int* in_sizes, int n_in,
                              void* d_out, int out_size, void* d_ws, size_t ws_size,
                              hipStream_t stream) {
    (void)in_sizes; (void)n_in; (void)d_ws; (void)ws_size; (void)out_size;
    const float* w0 = (const float*)d_in[0];
    const float* b0 = (const float*)d_in[1];
    const float* w1 = (const float*)d_in[2];
    const float* b1 = (const float*)d_in[3];
    const float* w2 = (const float*)d_in[4];
    const float* b2 = (const float*)d_in[5];
    const float* w3 = (const float*)d_in[6];
    const float* b3 = (const float*)d_in[7];
    const float* w4 = (const float*)d_in[8];
    const float* b4 = (const float*)d_in[9];
    const float* wt = (const float*)d_in[10];
    const float* x  = (const float*)d_in[11];
    float* out = (float*)d_out;

    dim3 grid(NBLK), block(64);
    hipLaunchKernelGGL(phinn_kernel, grid, block, 0, stream,
                       w0, b0, w1, b1, w2, b2, w3, b3, w4, b4, wt, x, out);
}

// Round 9
// 188.816 us; speedup vs baseline: 1.1226x; 1.1226x over previous
//
#include <hip/hip_runtime.h>

#define NDIM 2
#define NCELLS 200
#define BATCH 128
#define NPTS (BATCH * NCELLS)      /* 25600 */
#define NBLK (NPTS / 16)           /* 1600 waves, 16 points each */
#define XROW (2 + NCELLS * NDIM + 5) /* 407 */
#define DT_F 0.001f

typedef _Float16 v4h __attribute__((ext_vector_type(4)));
typedef _Float16 h2  __attribute__((ext_vector_type(2)));
typedef float    v4f __attribute__((ext_vector_type(4)));

#define MFMA16(A, B, C) __builtin_amdgcn_mfma_f32_16x16x16f16((A), (B), (C), 0, 0, 0)

__device__ __forceinline__ v4h pk4(const v4f v) {
    h2 lo = __builtin_bit_cast(h2, __builtin_amdgcn_cvt_pkrtz(v[0], v[1]));
    h2 hi = __builtin_bit_cast(h2, __builtin_amdgcn_cvt_pkrtz(v[2], v[3]));
    v4h r; r[0] = lo[0]; r[1] = lo[1]; r[2] = hi[0]; r[3] = hi[1];
    return r;
}

// softplus a = max(z,0) + log(1+e), sigma = (z>=0 ? 1 : e) * rcp(1+e),
// with e = exp(-|z|) shared. sigma path (rcp) runs parallel to log path.
__device__ __forceinline__ void act4(const v4f z, v4h& ah, v4h& qh) {
    v4f a, s;
    #pragma unroll
    for (int i = 0; i < 4; ++i) {
        float e = __expf(-fabsf(z[i]));
        float t = 1.0f + e;
        float L = __logf(t);
        float r = __builtin_amdgcn_rcpf(t);
        a[i] = fmaxf(z[i], 0.0f) + L;
        s[i] = (z[i] >= 0.0f) ? r : e * r;
    }
    ah = pk4(a);
    qh = pk4(s);
}

// sigma only (L4: softplus value itself is never needed) — no log.
__device__ __forceinline__ v4h sig4(const v4f z) {
    v4f s;
    #pragma unroll
    for (int i = 0; i < 4; ++i) {
        float e = __expf(-fabsf(z[i]));
        float r = __builtin_amdgcn_rcpf(1.0f + e);
        s[i] = (z[i] >= 0.0f) ? r : e * r;
    }
    return pk4(s);
}

// MFMA 16x16x16 f16 layouts (m89-verified family):
//   A[m][k]: m = lane&15, k = (lane>>4)*4 + i
//   B[k][n]: n = lane&15, k = (lane>>4)*4 + i
//   C/D[m][n]: n = lane&15, m = (lane>>4)*4 + reg
// D of one layer == B-layout of the next -> no cross-lane movement, no LDS.
// 16 points/wave (1600 waves): r7 showed 2 chains/wave serialize (VGPR=76)
// and halved TLP — 1.56 waves/SIMD beats 0.78 with "ILP".

__global__ void __launch_bounds__(64, 1) phinn_kernel(
    const float* __restrict__ w0, const float* __restrict__ b0,
    const float* __restrict__ w1, const float* __restrict__ b1,
    const float* __restrict__ w2, const float* __restrict__ b2,
    const float* __restrict__ w3, const float* __restrict__ b3,
    const float* __restrict__ w4, const float* __restrict__ b4,
    const float* __restrict__ wt, const float* __restrict__ x,
    float* __restrict__ out)
{
    const int lane = threadIdx.x;     // 1 wave per block
    const int g = lane >> 4;          // k-group 0..3
    const int m = lane & 15;          // row (A) / col (B,C/D) index
    const int p = blockIdx.x * 16 + m;

    // ---------- one-time weight fragment preload (registers, f16) ----------
    v4h fW0, fW0T, fW1[2], fW1T[2], fW2[2][2], fW2T[2][2], fW3[2], fW3T[2];
    #pragma unroll
    for (int i = 0; i < 4; ++i) {
        const int k = 4 * g + i;
        fW0[i] = (k < 2) ? (_Float16)w0[m * 2 + k] : (_Float16)0.f;
        #pragma unroll
        for (int t = 0; t < 2; ++t) {
            fW1[t][i]  = (_Float16)w1[(16 * t + m) * 16 + k];
            fW3[t][i]  = (_Float16)w3[m * 32 + 16 * t + k];
            fW1T[t][i] = (_Float16)w1[(16 * t + k) * 16 + m];
            fW3T[t][i] = (_Float16)w3[k * 32 + 16 * t + m];
            #pragma unroll
            for (int u = 0; u < 2; ++u) {
                fW2[t][u][i]  = (_Float16)w2[(16 * t + m) * 32 + 16 * u + k];
                fW2T[t][u][i] = (_Float16)w2[(16 * u + k) * 32 + 16 * t + m];
            }
        }
        fW0T[i] = (m < 2) ? (_Float16)w0[k * 2 + m] : (_Float16)0.f;
    }
    v4f b0a, b1a0, b1a1, b2a0, b2a1, b3a;
    v4h w4h;
    #pragma unroll
    for (int r = 0; r < 4; ++r) {
        b0a[r]  = b0[4 * g + r];
        b1a0[r] = b1[4 * g + r];   b1a1[r] = b1[16 + 4 * g + r];
        b2a0[r] = b2[4 * g + r];   b2a1[r] = b2[16 + 4 * g + r];
        b3a[r]  = b3[4 * g + r];
        w4h[r]  = (_Float16)w4[4 * g + r];
    }
    const float wt00 = wt[0], wt01 = wt[1], wt10 = wt[2], wt11 = wt[3];

    // ---------- per-point state ----------
    const int bi = p / NCELLS;
    const int ci = p - bi * NCELLS;
    const float* xr = x + bi * XROW;
    float y0 = xr[2 + 2 * ci];
    float y1 = xr[3 + 2 * ci];
    float ts = xr[0];
    const float sp0    = xr[XROW - 5];
    const float sg_lo0 = xr[XROW - 4], sg_lo1 = xr[XROW - 3];
    const float sg_hi0 = xr[XROW - 2], sg_hi1 = xr[XROW - 1];
    const float tl0 = sg_lo0 * wt00 + sg_lo1 * wt01;
    const float tl1 = sg_lo0 * wt10 + sg_lo1 * wt11;
    const float th0 = sg_hi0 * wt00 + sg_hi1 * wt01;
    const float th1 = sg_hi0 * wt10 + sg_hi1 * wt11;

    const int nsteps = (int)((x[1] - x[0]) / DT_F + 0.5f);
    const v4f zf = {0.f, 0.f, 0.f, 0.f};
    const bool g0 = (g == 0);

    v4h fY;
    fY[0] = g0 ? (_Float16)y0 : (_Float16)0.f;
    fY[1] = g0 ? (_Float16)y1 : (_Float16)0.f;
    fY[2] = (_Float16)0.f; fY[3] = (_Float16)0.f;

    #pragma unroll 1
    for (int it = 0; it < nsteps; ++it) {
        // ---- forward ----
        v4f z1 = MFMA16(fW0, fY, b0a);
        v4h a1h, q1h; act4(z1, a1h, q1h);

        v4f z20 = MFMA16(fW1[0], a1h, b1a0);
        v4f z21 = MFMA16(fW1[1], a1h, b1a1);
        v4h a2h0, q2h0; act4(z20, a2h0, q2h0);
        v4h a2h1, q2h1; act4(z21, a2h1, q2h1);

        v4f z30 = MFMA16(fW2[0][0], a2h0, b2a0);
        z30 = MFMA16(fW2[0][1], a2h1, z30);
        v4f z31 = MFMA16(fW2[1][0], a2h0, b2a1);
        z31 = MFMA16(fW2[1][1], a2h1, z31);
        v4h a3h0, q3h0; act4(z30, a3h0, q3h0);
        v4h a3h1, q3h1; act4(z31, a3h1, q3h1);

        v4f z4 = MFMA16(fW3[0], a3h0, b3a);
        z4 = MFMA16(fW3[1], a3h1, z4);

        // ---- backward (all sigma multiplies packed f16) ----
        v4h g4h = sig4(z4) * w4h;

        v4f s0 = MFMA16(fW3T[0], g4h, zf);
        v4f s1 = MFMA16(fW3T[1], g4h, zf);
        v4h g3h0 = pk4(s0) * q3h0;
        v4h g3h1 = pk4(s1) * q3h1;

        v4f u0 = MFMA16(fW2T[0][0], g3h0, zf);
        u0 = MFMA16(fW2T[0][1], g3h1, u0);
        v4f u1 = MFMA16(fW2T[1][0], g3h0, zf);
        u1 = MFMA16(fW2T[1][1], g3h1, u1);
        v4h g2h0 = pk4(u0) * q2h0;
        v4h g2h1 = pk4(u1) * q2h1;

        v4f w = MFMA16(fW1T[0], g2h0, zf);
        w = MFMA16(fW1T[1], g2h1, w);
        v4h g1h = pk4(w) * q1h;

        v4f gy = MFMA16(fW0T, g1h, zf);

        const bool lo = ts < sp0;
        const float tilt0 = lo ? tl0 : th0;
        const float tilt1 = lo ? tl1 : th1;
        y0 = fmaf(-(gy[0] + tilt0), DT_F, y0);
        y1 = fmaf(-(gy[1] + tilt1), DT_F, y1);
        ts += DT_F;

        fY[0] = g0 ? (_Float16)y0 : (_Float16)0.f;
        fY[1] = g0 ? (_Float16)y1 : (_Float16)0.f;
    }

    if (g0) {
        out[2 * p + 0] = y0;
        out[2 * p + 1] = y1;
    }
}

extern "C" void kernel_launch(void* const* d_in, const int* in_sizes, int n_in,
                              void* d_out, int out_size, void* d_ws, size_t ws_size,
                              hipStream_t stream) {
    (void)in_sizes; (void)n_in; (void)d_ws; (void)ws_size; (void)out_size;
    const float* w0 = (const float*)d_in[0];
    const float* b0 = (const float*)d_in[1];
    const float* w1 = (const float*)d_in[2];
    const float* b1 = (const float*)d_in[3];
    const float* w2 = (const float*)d_in[4];
    const float* b2 = (const float*)d_in[5];
    const float* w3 = (const float*)d_in[6];
    const float* b3 = (const float*)d_in[7];
    const float* w4 = (const float*)d_in[8];
    const float* b4 = (const float*)d_in[9];
    const float* wt = (const float*)d_in[10];
    const float* x  = (const float*)d_in[11];
    float* out = (float*)d_out;

    dim3 grid(NBLK), block(64);
    hipLaunchKernelGGL(phinn_kernel, grid, block, 0, stream,
                       w0, b0, w1, b1, w2, b2, w3, b3, w4, b4, wt, x, out);
}

// Round 10
// 160.955 us; speedup vs baseline: 1.3170x; 1.1731x over previous
//
#include <hip/hip_runtime.h>

#define NDIM 2
#define NCELLS 200
#define BATCH 128
#define NPTS (BATCH * NCELLS)      /* 25600 */
#define NBLK (NPTS / 16)           /* 1600 waves, 16 points each */
#define XROW (2 + NCELLS * NDIM + 5) /* 407 */
#define DT_F 0.001f
#define LOG2E 1.4426950408889634f
#define LN2   0.6931471805599453f

typedef _Float16 v4h __attribute__((ext_vector_type(4)));
typedef _Float16 h2  __attribute__((ext_vector_type(2)));
typedef float    v4f __attribute__((ext_vector_type(4)));

#define MFMA16(A, B, C) __builtin_amdgcn_mfma_f32_16x16x16f16((A), (B), (C), 0, 0, 0)

__device__ __forceinline__ v4h pk4(const v4f v) {
    h2 lo = __builtin_bit_cast(h2, __builtin_amdgcn_cvt_pkrtz(v[0], v[1]));
    h2 hi = __builtin_bit_cast(h2, __builtin_amdgcn_cvt_pkrtz(v[2], v[3]));
    return __builtin_shufflevector(lo, hi, 0, 1, 2, 3);
}

// Raw-instruction softplus/sigmoid (round-9 lesson: __expf/__logf were NOT
// single v_exp/v_log here — ~1.5k hidden libm insts/step made us issue-bound).
//   e = exp2(-|z|*log2e)            (1 mul w/ modifiers + v_exp_f32)
//   a = max(z,0) + log2(1+e)*ln2    (v_add, v_log_f32, v_max, v_fma)
//   s = (z>=0 ? 1 : e) * rcp(1+e)   (v_rcp_f32, v_mul, v_cmp, v_cndmask)
__device__ __forceinline__ void act4(const v4f z, v4h& ah, v4h& qh) {
    v4f a, s;
    #pragma unroll
    for (int i = 0; i < 4; ++i) {
        float e = __builtin_amdgcn_exp2f(-fabsf(z[i]) * LOG2E);
        float t = 1.0f + e;
        float L = __builtin_amdgcn_logf(t);          // log2(t)
        float r = __builtin_amdgcn_rcpf(t);
        a[i] = fmaf(L, LN2, fmaxf(z[i], 0.0f));
        s[i] = (z[i] >= 0.0f) ? r : e * r;
    }
    ah = pk4(a);
    qh = pk4(s);
}

// sigma only (L4: softplus value never needed) — no log.
__device__ __forceinline__ v4h sig4(const v4f z) {
    v4f s;
    #pragma unroll
    for (int i = 0; i < 4; ++i) {
        float e = __builtin_amdgcn_exp2f(-fabsf(z[i]) * LOG2E);
        float r = __builtin_amdgcn_rcpf(1.0f + e);
        s[i] = (z[i] >= 0.0f) ? r : e * r;
    }
    return pk4(s);
}

// MFMA 16x16x16 f16 layouts (m89-verified family):
//   A[m][k]: m = lane&15, k = (lane>>4)*4 + i
//   B[k][n]: n = lane&15, k = (lane>>4)*4 + i
//   C/D[m][n]: n = lane&15, m = (lane>>4)*4 + reg
// D of one layer == B-layout of the next -> no cross-lane movement, no LDS.
// 16 points/wave (1600 waves): r7 showed 2 chains/wave serialize (VGPR=76)
// and halved TLP — 1.56 waves/SIMD beats 0.78 with "ILP".

__global__ void __launch_bounds__(64, 1) phinn_kernel(
    const float* __restrict__ w0, const float* __restrict__ b0,
    const float* __restrict__ w1, const float* __restrict__ b1,
    const float* __restrict__ w2, const float* __restrict__ b2,
    const float* __restrict__ w3, const float* __restrict__ b3,
    const float* __restrict__ w4, const float* __restrict__ b4,
    const float* __restrict__ wt, const float* __restrict__ x,
    float* __restrict__ out)
{
    const int lane = threadIdx.x;     // 1 wave per block
    const int g = lane >> 4;          // k-group 0..3
    const int m = lane & 15;          // row (A) / col (B,C/D) index
    const int p = blockIdx.x * 16 + m;

    // ---------- one-time weight fragment preload (registers, f16) ----------
    v4h fW0, fW0T, fW1[2], fW1T[2], fW2[2][2], fW2T[2][2], fW3[2], fW3T[2];
    #pragma unroll
    for (int i = 0; i < 4; ++i) {
        const int k = 4 * g + i;
        fW0[i] = (k < 2) ? (_Float16)w0[m * 2 + k] : (_Float16)0.f;
        #pragma unroll
        for (int t = 0; t < 2; ++t) {
            fW1[t][i]  = (_Float16)w1[(16 * t + m) * 16 + k];
            fW3[t][i]  = (_Float16)w3[m * 32 + 16 * t + k];
            fW1T[t][i] = (_Float16)w1[(16 * t + k) * 16 + m];
            fW3T[t][i] = (_Float16)w3[k * 32 + 16 * t + m];
            #pragma unroll
            for (int u = 0; u < 2; ++u) {
                fW2[t][u][i]  = (_Float16)w2[(16 * t + m) * 32 + 16 * u + k];
                fW2T[t][u][i] = (_Float16)w2[(16 * u + k) * 32 + 16 * t + m];
            }
        }
        fW0T[i] = (m < 2) ? (_Float16)w0[k * 2 + m] : (_Float16)0.f;
    }
    v4f b0a, b1a0, b1a1, b2a0, b2a1, b3a;
    v4h w4h;
    #pragma unroll
    for (int r = 0; r < 4; ++r) {
        b0a[r]  = b0[4 * g + r];
        b1a0[r] = b1[4 * g + r];   b1a1[r] = b1[16 + 4 * g + r];
        b2a0[r] = b2[4 * g + r];   b2a1[r] = b2[16 + 4 * g + r];
        b3a[r]  = b3[4 * g + r];
        w4h[r]  = (_Float16)w4[4 * g + r];
    }
    const float wt00 = wt[0], wt01 = wt[1], wt10 = wt[2], wt11 = wt[3];

    // ---------- per-point state ----------
    const int bi = p / NCELLS;
    const int ci = p - bi * NCELLS;
    const float* xr = x + bi * XROW;
    float y0 = xr[2 + 2 * ci];
    float y1 = xr[3 + 2 * ci];
    float ts = xr[0];
    const float sp0    = xr[XROW - 5];
    const float sg_lo0 = xr[XROW - 4], sg_lo1 = xr[XROW - 3];
    const float sg_hi0 = xr[XROW - 2], sg_hi1 = xr[XROW - 1];
    const float tl0 = sg_lo0 * wt00 + sg_lo1 * wt01;
    const float tl1 = sg_lo0 * wt10 + sg_lo1 * wt11;
    const float th0 = sg_hi0 * wt00 + sg_hi1 * wt01;
    const float th1 = sg_hi0 * wt10 + sg_hi1 * wt11;

    const int nsteps = (int)((x[1] - x[0]) / DT_F + 0.5f);
    const v4f zf = {0.f, 0.f, 0.f, 0.f};
    const bool g0 = (g == 0);

    v4h fY;
    fY[0] = g0 ? (_Float16)y0 : (_Float16)0.f;
    fY[1] = g0 ? (_Float16)y1 : (_Float16)0.f;
    fY[2] = (_Float16)0.f; fY[3] = (_Float16)0.f;

    #pragma unroll 1
    for (int it = 0; it < nsteps; ++it) {
        // ---- forward ----
        v4f z1 = MFMA16(fW0, fY, b0a);
        v4h a1h, q1h; act4(z1, a1h, q1h);

        v4f z20 = MFMA16(fW1[0], a1h, b1a0);
        v4f z21 = MFMA16(fW1[1], a1h, b1a1);
        v4h a2h0, q2h0; act4(z20, a2h0, q2h0);
        v4h a2h1, q2h1; act4(z21, a2h1, q2h1);

        v4f z30 = MFMA16(fW2[0][0], a2h0, b2a0);
        z30 = MFMA16(fW2[0][1], a2h1, z30);
        v4f z31 = MFMA16(fW2[1][0], a2h0, b2a1);
        z31 = MFMA16(fW2[1][1], a2h1, z31);
        v4h a3h0, q3h0; act4(z30, a3h0, q3h0);
        v4h a3h1, q3h1; act4(z31, a3h1, q3h1);

        v4f z4 = MFMA16(fW3[0], a3h0, b3a);
        z4 = MFMA16(fW3[1], a3h1, z4);

        // ---- backward (all sigma multiplies packed f16) ----
        v4h g4h = sig4(z4) * w4h;

        v4f s0 = MFMA16(fW3T[0], g4h, zf);
        v4f s1 = MFMA16(fW3T[1], g4h, zf);
        v4h g3h0 = pk4(s0) * q3h0;
        v4h g3h1 = pk4(s1) * q3h1;

        v4f u0 = MFMA16(fW2T[0][0], g3h0, zf);
        u0 = MFMA16(fW2T[0][1], g3h1, u0);
        v4f u1 = MFMA16(fW2T[1][0], g3h0, zf);
        u1 = MFMA16(fW2T[1][1], g3h1, u1);
        v4h g2h0 = pk4(u0) * q2h0;
        v4h g2h1 = pk4(u1) * q2h1;

        v4f w = MFMA16(fW1T[0], g2h0, zf);
        w = MFMA16(fW1T[1], g2h1, w);
        v4h g1h = pk4(w) * q1h;

        v4f gy = MFMA16(fW0T, g1h, zf);

        const bool lo = ts < sp0;
        const float tilt0 = lo ? tl0 : th0;
        const float tilt1 = lo ? tl1 : th1;
        y0 = fmaf(-(gy[0] + tilt0), DT_F, y0);
        y1 = fmaf(-(gy[1] + tilt1), DT_F, y1);
        ts += DT_F;

        fY[0] = g0 ? (_Float16)y0 : (_Float16)0.f;
        fY[1] = g0 ? (_Float16)y1 : (_Float16)0.f;
    }

    if (g0) {
        out[2 * p + 0] = y0;
        out[2 * p + 1] = y1;
    }
}

extern "C" void kernel_launch(void* const* d_in, const int* in_sizes, int n_in,
                              void* d_out, int out_size, void* d_ws, size_t ws_size,
                              hipStream_t stream) {
    (void)in_sizes; (void)n_in; (void)d_ws; (void)ws_size; (void)out_size;
    const float* w0 = (const float*)d_in[0];
    const float* b0 = (const float*)d_in[1];
    const float* w1 = (const float*)d_in[2];
    const float* b1 = (const float*)d_in[3];
    const float* w2 = (const float*)d_in[4];
    const float* b2 = (const float*)d_in[5];
    const float* w3 = (const float*)d_in[6];
    const float* b3 = (const float*)d_in[7];
    const float* w4 = (const float*)d_in[8];
    const float* b4 = (const float*)d_in[9];
    const float* wt = (const float*)d_in[10];
    const float* x  = (const float*)d_in[11];
    float* out = (float*)d_out;

    dim3 grid(NBLK), block(64);
    hipLaunchKernelGGL(phinn_kernel, grid, block, 0, stream,
                       w0, b0, w1, b1, w2, b2, w3, b3, w4, b4, wt, x, out);
}